// Round 2
// baseline (580.909 us; speedup 1.0000x reference)
//
#include <hip/hip_runtime.h>
#include <hip/hip_bf16.h>

typedef __bf16 bf16_t;
typedef __bf16 bf16x8 __attribute__((ext_vector_type(8)));
typedef __bf16 bf16x4 __attribute__((ext_vector_type(4)));
typedef float f32x4 __attribute__((ext_vector_type(4)));

#define B_ 16
#define T_ 128
#define H_ 512
#define L_ 2
#define V_ 32000
#define G_ 2048   /* 4*H */
#define M_ 2048   /* B*T */

#define BM 128
#define BN 128
#define BK 32

__device__ __forceinline__ float sigf(float x) { return 1.f / (1.f + __expf(-x)); }
__device__ __forceinline__ float tanhf_(float x) { return 2.f / (1.f + __expf(-2.f * x)) - 1.f; }

// ---------------------------------------------------------------------------
// prep: one kernel, block-range partitioned.
//   [0,2048)      : W_ih fp32->bf16 with gate-interleave permute
//   [2048,18048)  : W_out fp32->bf16
//   [18048,19072) : x = relu(embedding[tokens]) -> bf16
//   [19072,19328) : biasall = b_ih + b_hh + h0 @ W_hh^T  (gate-interleaved)
// Gate-interleave: row' = (hh>>4)*64 + gate*16 + (hh&15), so in the GEMM
// epilogue gate==ni and hh==((tileN+wn*64)>>2)+r16 for every lane.
// ---------------------------------------------------------------------------
__global__ __launch_bounds__(256) void prep_kernel(
    const float* __restrict__ W_ih, const float* __restrict__ W_out,
    const float* __restrict__ emb,  const int* __restrict__ target,
    const float* __restrict__ enc_h, const float* __restrict__ W_hh,
    const float* __restrict__ b_ih, const float* __restrict__ b_hh,
    bf16_t* __restrict__ wih_b, bf16_t* __restrict__ wout_b,
    bf16_t* __restrict__ xa, float* __restrict__ biasall)
{
    const int bid = blockIdx.x;
    const int tid = threadIdx.x;

    if (bid < 2048) {
        // ---- W_ih convert + permute (L_*G_*H_/4 = 524288 float4 threads) ----
        int t = bid * 256 + tid;
        int l = t >> 18;                 // G_*H_/4 = 262144
        int r = t & 262143;
        int rowp = r >> 7;               // permuted row 0..2047
        int k  = (r & 127) << 2;
        int hhblock = rowp >> 6;
        int gate    = (rowp >> 4) & 3;
        int hhlocal = rowp & 15;
        int gorig = gate * H_ + hhblock * 16 + hhlocal;
        float4 v = *(const float4*)(W_ih + ((size_t)l * G_ + gorig) * H_ + k);
        bf16x4 o;
        o[0] = (bf16_t)v.x; o[1] = (bf16_t)v.y; o[2] = (bf16_t)v.z; o[3] = (bf16_t)v.w;
        *(bf16x4*)(wih_b + ((size_t)l * G_ + rowp) * H_ + k) = o;
    } else if (bid < 18048) {
        // ---- W_out convert (V_*H_/4 = 4,096,000 float4 threads) ----
        int t = (bid - 2048) * 256 + tid;
        float4 v = ((const float4*)W_out)[t];
        bf16x4 o;
        o[0] = (bf16_t)v.x; o[1] = (bf16_t)v.y; o[2] = (bf16_t)v.z; o[3] = (bf16_t)v.w;
        ((bf16x4*)wout_b)[t] = o;
    } else if (bid < 19072) {
        // ---- embedding gather + relu ----
        int idx = (bid - 18048) * 256 + tid;   // M_*(H_/4)
        int m  = idx >> 7;
        int h4 = (idx & 127) << 2;
        int b = m >> 7, tt = m & 127;
        int tok = (tt == 0) ? 1 : target[b * T_ + tt - 1];
        float4 v = *(const float4*)(emb + (size_t)tok * H_ + h4);
        bf16x4 o;
        o[0] = (bf16_t)fmaxf(v.x, 0.f);
        o[1] = (bf16_t)fmaxf(v.y, 0.f);
        o[2] = (bf16_t)fmaxf(v.z, 0.f);
        o[3] = (bf16_t)fmaxf(v.w, 0.f);
        *(bf16x4*)(xa + (size_t)m * H_ + h4) = o;
    } else {
        // ---- hproj bias table, gate-interleaved store ----
        int idx = (bid - 19072) * 256 + tid;   // L_*G_*B_ = 65536
        int b = idx & 15;
        int g = (idx >> 4) & (G_ - 1);
        int l = idx >> 15;
        const float* hrow = enc_h + ((size_t)l * B_ + b) * H_;
        const float* wrow = W_hh + ((size_t)l * G_ + g) * H_;
        float acc = b_ih[l * G_ + g] + b_hh[l * G_ + g];
        #pragma unroll 4
        for (int k = 0; k < H_; k += 4) {
            float4 hv = *(const float4*)(hrow + k);
            float4 wv = *(const float4*)(wrow + k);
            acc += hv.x * wv.x + hv.y * wv.y + hv.z * wv.z + hv.w * wv.w;
        }
        int gate = g >> 9;
        int hh = g & (H_ - 1);
        int rowp = ((hh >> 4) << 6) + (gate << 4) + (hh & 15);
        biasall[((size_t)l * B_ + b) * G_ + rowp] = acc;
    }
}

// ---------------------------------------------------------------------------
// Fused gates GEMM + LSTM cell.  A: x (M_ x H_ bf16), Bw: interleaved W_ih[l].
// BM == T_ so blockIdx.x == batch index b.
// ---------------------------------------------------------------------------
__global__ __launch_bounds__(256) void gemm_gates(
    const bf16_t* __restrict__ A, const bf16_t* __restrict__ Bw,
    const float* __restrict__ biasL, const float* __restrict__ enc_c,
    bf16_t* __restrict__ xout, float* __restrict__ out_h, float* __restrict__ out_c,
    int l)
{
    __shared__ __align__(16) bf16_t As[BM * BK];
    __shared__ __align__(16) bf16_t Bs[BN * BK];

    const int tid  = threadIdx.x;
    const int lane = tid & 63;
    const int wave = tid >> 6;
    const int wm = wave >> 1, wn = wave & 1;
    const int quad = lane >> 4;
    const int r16  = lane & 15;

    const int tileM = blockIdx.x * BM;
    const int tileN = blockIdx.y * BN;

    const int srow = lane >> 2;
    const int scol = (lane & 3) * 8;

    f32x4 acc[4][4];
    #pragma unroll
    for (int i = 0; i < 4; i++)
        #pragma unroll
        for (int j = 0; j < 4; j++) acc[i][j] = (f32x4){0.f, 0.f, 0.f, 0.f};

    for (int kt = 0; kt < H_ / BK; ++kt) {
        const int k0 = kt * BK;
        #pragma unroll
        for (int j = 0; j < 2; ++j) {
            const int r0 = j * 64 + wave * 16;
            const bf16_t* ga = A  + (size_t)(tileM + r0 + srow) * H_ + k0 + scol;
            const bf16_t* gb = Bw + (size_t)(tileN + r0 + srow) * H_ + k0 + scol;
            __builtin_amdgcn_global_load_lds(
                (const __attribute__((address_space(1))) void*)ga,
                (__attribute__((address_space(3))) void*)(As + r0 * BK), 16, 0, 0);
            __builtin_amdgcn_global_load_lds(
                (const __attribute__((address_space(1))) void*)gb,
                (__attribute__((address_space(3))) void*)(Bs + r0 * BK), 16, 0, 0);
        }
        __syncthreads();

        bf16x8 af[4], bfr[4];
        #pragma unroll
        for (int mi = 0; mi < 4; mi++)
            af[mi] = *(const bf16x8*)(As + (wm * 64 + mi * 16 + r16) * BK + quad * 8);
        #pragma unroll
        for (int ni = 0; ni < 4; ni++)
            bfr[ni] = *(const bf16x8*)(Bs + (wn * 64 + ni * 16 + r16) * BK + quad * 8);
        #pragma unroll
        for (int mi = 0; mi < 4; mi++)
            #pragma unroll
            for (int ni = 0; ni < 4; ni++)
                acc[mi][ni] = __builtin_amdgcn_mfma_f32_16x16x32_bf16(
                    af[mi], bfr[ni], acc[mi][ni], 0, 0, 0);
        __syncthreads();
    }

    // ---- fused LSTM cell epilogue (gate == ni thanks to interleave) ----
    const int b = blockIdx.x;
    const float* brow = biasL + (size_t)b * G_;
    const int hh = ((tileN + wn * 64) >> 2) + r16;
    const float c0 = enc_c[((size_t)l * B_ + b) * H_ + hh];
    float bv[4];
    #pragma unroll
    for (int ni = 0; ni < 4; ni++)
        bv[ni] = brow[tileN + wn * 64 + ni * 16 + r16];

    #pragma unroll
    for (int mi = 0; mi < 4; mi++) {
        #pragma unroll
        for (int rr = 0; rr < 4; rr++) {
            float vi = acc[mi][0][rr] + bv[0];
            float vf = acc[mi][1][rr] + bv[1];
            float vg = acc[mi][2][rr] + bv[2];
            float vo = acc[mi][3][rr] + bv[3];
            float cs = sigf(vf) * c0 + sigf(vi) * tanhf_(vg);
            float h  = sigf(vo) * tanhf_(cs);
            int row = tileM + wm * 64 + mi * 16 + quad * 4 + rr;
            xout[(size_t)row * H_ + hh] = (bf16_t)h;
            if ((row & (T_ - 1)) == T_ - 1) {
                out_h[((size_t)l * B_ + b) * H_ + hh] = h;
                out_c[((size_t)l * B_ + b) * H_ + hh] = cs;
            }
        }
    }
}

// ---------------------------------------------------------------------------
// Logits GEMM:  C(MxN) = A(MxK) @ B(NxK)^T + bias[col]
// ---------------------------------------------------------------------------
__global__ __launch_bounds__(256) void gemm_bt(const bf16_t* __restrict__ A,
                                               const bf16_t* __restrict__ B,
                                               float* __restrict__ C,
                                               const float* __restrict__ bias,
                                               int M, int N, int K) {
    __shared__ __align__(16) bf16_t As[BM * BK];
    __shared__ __align__(16) bf16_t Bs[BN * BK];

    const int tid  = threadIdx.x;
    const int lane = tid & 63;
    const int wave = tid >> 6;
    const int wm = wave >> 1, wn = wave & 1;
    const int quad = lane >> 4;
    const int r16  = lane & 15;

    const int tileM = blockIdx.x * BM;
    const int tileN = blockIdx.y * BN;

    const int srow = lane >> 2;
    const int scol = (lane & 3) * 8;

    f32x4 acc[4][4];
    #pragma unroll
    for (int i = 0; i < 4; i++)
        #pragma unroll
        for (int j = 0; j < 4; j++) acc[i][j] = (f32x4){0.f, 0.f, 0.f, 0.f};

    const int nk = K / BK;
    for (int kt = 0; kt < nk; ++kt) {
        const int k0 = kt * BK;
        #pragma unroll
        for (int j = 0; j < 2; ++j) {
            const int r0 = j * 64 + wave * 16;
            const bf16_t* ga = A + (size_t)(tileM + r0 + srow) * K + k0 + scol;
            const bf16_t* gb = B + (size_t)(tileN + r0 + srow) * K + k0 + scol;
            __builtin_amdgcn_global_load_lds(
                (const __attribute__((address_space(1))) void*)ga,
                (__attribute__((address_space(3))) void*)(As + r0 * BK), 16, 0, 0);
            __builtin_amdgcn_global_load_lds(
                (const __attribute__((address_space(1))) void*)gb,
                (__attribute__((address_space(3))) void*)(Bs + r0 * BK), 16, 0, 0);
        }
        __syncthreads();

        bf16x8 af[4], bfr[4];
        #pragma unroll
        for (int mi = 0; mi < 4; mi++)
            af[mi] = *(const bf16x8*)(As + (wm * 64 + mi * 16 + r16) * BK + quad * 8);
        #pragma unroll
        for (int ni = 0; ni < 4; ni++)
            bfr[ni] = *(const bf16x8*)(Bs + (wn * 64 + ni * 16 + r16) * BK + quad * 8);
        #pragma unroll
        for (int mi = 0; mi < 4; mi++)
            #pragma unroll
            for (int ni = 0; ni < 4; ni++)
                acc[mi][ni] = __builtin_amdgcn_mfma_f32_16x16x32_bf16(
                    af[mi], bfr[ni], acc[mi][ni], 0, 0, 0);
        __syncthreads();
    }

    float bv[4];
    #pragma unroll
    for (int ni = 0; ni < 4; ni++)
        bv[ni] = bias[tileN + wn * 64 + ni * 16 + r16];

    #pragma unroll
    for (int mi = 0; mi < 4; mi++) {
        #pragma unroll
        for (int ni = 0; ni < 4; ni++) {
            const int col = tileN + wn * 64 + ni * 16 + r16;
            #pragma unroll
            for (int rr = 0; rr < 4; rr++) {
                const int row = tileM + wm * 64 + mi * 16 + quad * 4 + rr;
                C[(size_t)row * N + col] = acc[mi][ni][rr] + bv[ni];
            }
        }
    }
}

extern "C" void kernel_launch(void* const* d_in, const int* in_sizes, int n_in,
                              void* d_out, int out_size, void* d_ws, size_t ws_size,
                              hipStream_t stream) {
    const float* enc_h  = (const float*)d_in[1];
    const float* enc_c  = (const float*)d_in[2];
    const int*   target = (const int*)d_in[3];
    const float* emb    = (const float*)d_in[4];
    const float* W_ih   = (const float*)d_in[5];
    const float* W_hh   = (const float*)d_in[6];
    const float* b_ih   = (const float*)d_in[7];
    const float* b_hh   = (const float*)d_in[8];
    const float* W_out  = (const float*)d_in[9];
    const float* b_out  = (const float*)d_in[10];
    float* out = (float*)d_out;

    // workspace layout
    char* w = (char*)d_ws;
    bf16_t* xa      = (bf16_t*)(w);                 // 2 MB
    bf16_t* xb      = (bf16_t*)(w + 2097152);       // 2 MB
    bf16_t* wih_b   = (bf16_t*)(w + 4194304);       // 4 MB (gate-interleaved)
    bf16_t* wout_b  = (bf16_t*)(w + 8388608);       // 32.77 MB
    float*  biasall = (float*)(w + 41156608);       // 256 KB (gate-interleaved)

    float* out_h = out + (size_t)M_ * V_;
    float* out_c = out_h + (size_t)L_ * B_ * H_;

    prep_kernel<<<19328, 256, 0, stream>>>(W_ih, W_out, emb, target, enc_h, W_hh,
                                           b_ih, b_hh, wih_b, wout_b, xa, biasall);

    gemm_gates<<<dim3(M_ / BM, G_ / BN), 256, 0, stream>>>(
        xa, wih_b, biasall, enc_c, xb, out_h, out_c, 0);
    gemm_gates<<<dim3(M_ / BM, G_ / BN), 256, 0, stream>>>(
        xb, wih_b + (size_t)G_ * H_, biasall + (size_t)B_ * G_, enc_c, xa, out_h, out_c, 1);

    gemm_bt<<<dim3(M_ / BM, V_ / BN), 256, 0, stream>>>(
        xa, wout_b, out, b_out, M_, V_, H_);
}